// Round 1
// baseline (4726.138 us; speedup 1.0000x reference)
//
#include <hip/hip_runtime.h>
#include <math.h>

// ---------------------------------------------------------------------------
// PixelCNN (5 gated residual blocks) + discretized-mixture-of-logistics logprob
// fp32 correctness-first implementation.
//   samples (16,3,64,64) -> x = 2s-1
//   h = conv7x7_maskA(x, w_in)                    [24 taps]
//   5x: g = conv3x3_maskB(relu(h), w_blk[i]);     [5 taps]  h += tanh(a)*sig(b)
//   h2 = relu(conv1x1(relu(h), w_out1)); params = conv1x1(h2, w_out2)
//   out[b] = sum_{y,x} logsumexp_m( dmol terms )
// ---------------------------------------------------------------------------

static constexpr int BATCH = 16, FCH = 160, HH = 64, WW = 64;

// workspace layout (bytes), all 16B-aligned
static constexpr size_t X_OFF    = 0;                         // 16*3*4096*4   = 786432
static constexpr size_t WTIN_OFF = 786432;                    // 24*3*160*4    = 46080
static constexpr size_t WT1_OFF  = WTIN_OFF + 46080;          // 160*160*4     = 102400
static constexpr size_t WT2_OFF  = WT1_OFF + 102400;          // 160*128*4     = 81920
static constexpr size_t WTB_OFF  = WT2_OFF + 81920;           // 5*5*160*320*4 = 5120000
static constexpr size_t H0_OFF   = WTB_OFF + 5120000;         // 41943040
static constexpr size_t H1_OFF   = H0_OFF + 41943040ULL;      // 41943040 (params alias here)

__global__ void k_prep(const float* __restrict__ s, float* __restrict__ x, int n) {
    int i = blockIdx.x * 256 + threadIdx.x;
    if (i < n) x[i] = 2.f * s[i] - 1.f;
}

// w_blk (5,320,160,3,3) -> wT[i][tap5][ic160][oc320], mask-B taps only
__global__ void k_twtb(const float* __restrict__ w, float* __restrict__ wT) {
    int idx = blockIdx.x * 256 + threadIdx.x;
    if (idx >= 5 * 5 * 160 * 320) return;
    int oc = idx % 320; int t2 = idx / 320;
    int ic = t2 % 160; t2 /= 160;
    int tap = t2 % 5; int i = t2 / 5;
    const int ky[5] = {0,0,0,1,1}, kx[5] = {0,1,2,0,1};
    wT[idx] = w[(((size_t)(i * 320 + oc) * 160 + ic) * 3 + ky[tap]) * 3 + kx[tap]];
}

// w_in (160,3,7,7) -> wT[tap24][ic3][oc160], mask-A taps (rows 0..2 full, row 3 cols 0..2)
__global__ void k_twtin(const float* __restrict__ w, float* __restrict__ wT) {
    int idx = blockIdx.x * 256 + threadIdx.x;
    if (idx >= 24 * 3 * 160) return;
    int oc = idx % 160; int t2 = idx / 160;
    int ic = t2 % 3; int tap = t2 / 3;
    int ky, kx;
    if (tap < 21) { ky = tap / 7; kx = tap % 7; } else { ky = 3; kx = tap - 21; }
    wT[idx] = w[((oc * 3 + ic) * 7 + ky) * 7 + kx];
}

__global__ void k_tw1(const float* __restrict__ w, float* __restrict__ wT) { // [ic][oc] 160x160
    int idx = blockIdx.x * 256 + threadIdx.x;
    if (idx >= 160 * 160) return;
    int oc = idx % 160, ic = idx / 160;
    wT[idx] = w[oc * 160 + ic];
}

__global__ void k_tw2(const float* __restrict__ w, float* __restrict__ wT) { // [ic][128] zero-padded
    int idx = blockIdx.x * 256 + threadIdx.x;
    if (idx >= 160 * 128) return;
    int oc = idx % 128, ic = idx / 128;
    wT[idx] = (oc < 100) ? w[oc * 160 + ic] : 0.f;
}

// masked 7x7 input conv: grid (10, 64, 16), block 256. Each WG: 16 oc x 64 x.
__global__ __launch_bounds__(256) void k_convin(const float* __restrict__ x,
                                                const float* __restrict__ wT,
                                                float* __restrict__ h) {
    __shared__ float xin_s[3 * 4 * 72];   // [ic][row(y-3..y)][col 0..69], xg = col-3
    __shared__ float w_s[24 * 3 * 16];
    int b = blockIdx.z, y = blockIdx.y, oc0 = blockIdx.x * 16;
    int t = threadIdx.x;
    for (int idx = t; idx < 3 * 4 * 70; idx += 256) {
        int col = idx % 70; int r = (idx / 70) % 4; int ic = idx / 280;
        int xg = col - 3, yg = y + r - 3;
        float v = 0.f;
        if (xg >= 0 && xg < 64 && yg >= 0)
            v = x[((size_t)(b * 3 + ic) * 64 + yg) * 64 + xg];
        xin_s[(ic * 4 + r) * 72 + col] = v;
    }
    for (int idx = t; idx < 24 * 3 * 16; idx += 256) {
        int j = idx % 16; int ic = (idx / 16) % 3; int tap = idx / 48;
        w_s[idx] = wT[(tap * 3 + ic) * 160 + oc0 + j];
    }
    __syncthreads();
    int ch = t >> 4;          // 0..15
    int x0 = (t & 15) * 4;
    float acc[4] = {0.f, 0.f, 0.f, 0.f};
    #pragma unroll
    for (int ic = 0; ic < 3; ic++) {
        #pragma unroll
        for (int r = 0; r < 4; r++) {
            const float* rp = &xin_s[(ic * 4 + r) * 72 + x0];
            float v[10];
            *(float4*)&v[0] = *(const float4*)&rp[0];
            *(float4*)&v[4] = *(const float4*)&rp[4];
            *(float2*)&v[8] = *(const float2*)&rp[8];
            const int nd = (r < 3) ? 7 : 3;
            #pragma unroll
            for (int d = 0; d < 7; d++) {
                if (d < nd) {
                    int tap = (r < 3) ? (r * 7 + d) : (21 + d);
                    float wv = w_s[(tap * 3 + ic) * 16 + ch];
                    #pragma unroll
                    for (int j = 0; j < 4; j++) acc[j] += wv * v[d + j];
                }
            }
        }
    }
    size_t off = ((size_t)(b * 160 + oc0 + ch)) * 4096 + (size_t)y * 64 + x0;
    float4 o; o.x = acc[0]; o.y = acc[1]; o.z = acc[2]; o.w = acc[3];
    *(float4*)&h[off] = o;
}

// gated masked 3x3 block conv, fused gating + residual.
// grid (5, 64, 16): c0 = bx*32 pair-group; WG computes 64 out-ch (a:c0..c0+31, b:+160) x 64 x.
__global__ __launch_bounds__(256) void k_blk(const float* __restrict__ hin,
                                             float* __restrict__ hout,
                                             const float* __restrict__ wT) {
    __shared__ float w_s[5 * 32 * 64];    // [tap][ic][oc64]           40960 B
    __shared__ float in_s[32 * 2 * 68];   // [ic][row(y-1,y)][col 68]  17408 B
    int b = blockIdx.z, y = blockIdx.y, c0 = blockIdx.x * 32;
    int t = threadIdx.x;
    int co = (t >> 4) * 4;     // 0..60 within 64-channel tile
    int x0 = (t & 15) * 4;
    float acc[4][4] = {};
    for (int ic0 = 0; ic0 < 160; ic0 += 32) {
        for (int idx = t; idx < 5 * 32 * 64; idx += 256) {
            int oc64 = idx & 63; int ic = (idx >> 6) & 31; int tap = idx >> 11;
            int ocg = (oc64 < 32) ? (c0 + oc64) : (160 + c0 + (oc64 - 32));
            w_s[idx] = wT[(size_t)(tap * 160 + ic0 + ic) * 320 + ocg];
        }
        for (int idx = t; idx < 32 * 2 * 66; idx += 256) {
            int col = idx % 66; int r = (idx / 66) & 1; int ic = idx / 132;
            int xg = col - 1, yg = y + r - 1;
            float v = 0.f;
            if (xg >= 0 && xg < 64 && yg >= 0) {
                v = hin[((size_t)(b * 160 + ic0 + ic) * 64 + yg) * 64 + xg];
                v = fmaxf(v, 0.f);
            }
            in_s[(ic * 2 + r) * 68 + col] = v;
        }
        __syncthreads();
        #pragma unroll 4
        for (int ic = 0; ic < 32; ic++) {
            const float* r0 = &in_s[(ic * 2 + 0) * 68 + x0];
            const float* r1 = &in_s[(ic * 2 + 1) * 68 + x0];
            float v0[6], v1[5];
            *(float4*)&v0[0] = *(const float4*)&r0[0];
            *(float2*)&v0[4] = *(const float2*)&r0[4];
            *(float4*)&v1[0] = *(const float4*)&r1[0];
            v1[4] = r1[4];
            const float* wp = &w_s[ic * 64 + co];    // tap stride = 2048 floats
            #pragma unroll
            for (int tap = 0; tap < 5; tap++) {
                float4 wv = *(const float4*)&wp[tap * 2048];
                const float* vv = (tap < 3) ? &v0[tap] : &v1[tap - 3];
                const float* wc = (const float*)&wv;
                #pragma unroll
                for (int cc = 0; cc < 4; cc++) {
                    #pragma unroll
                    for (int j = 0; j < 4; j++) acc[cc][j] += wc[cc] * vv[j];
                }
            }
        }
        __syncthreads();
    }
    // pair a/b halves through LDS, apply gating + residual
    float* g_s = w_s;   // 64*64 floats
    #pragma unroll
    for (int cc = 0; cc < 4; cc++) {
        float4 o; o.x = acc[cc][0]; o.y = acc[cc][1]; o.z = acc[cc][2]; o.w = acc[cc][3];
        *(float4*)&g_s[(co + cc) * 64 + x0] = o;
    }
    __syncthreads();
    for (int idx = t; idx < 2048; idx += 256) {
        int xx = idx & 63; int c = idx >> 6;
        float av = g_s[c * 64 + xx];
        float bv = g_s[(c + 32) * 64 + xx];
        size_t off = ((size_t)(b * 160 + c0 + c) * 64 + y) * 64 + xx;
        hout[off] = hin[off] + tanhf(av) * (1.f / (1.f + expf(-bv)));
    }
}

// 1x1 conv: grid (ocGroups, 64, 16), block 128. WG: 32 oc x 64 x.
template <bool RELU_IN, bool RELU_OUT>
__global__ __launch_bounds__(128) void k_c1x1(const float* __restrict__ in,
                                              float* __restrict__ out,
                                              const float* __restrict__ wT,
                                              int inC, int wStride, int outC) {
    __shared__ float in_s[32 * 64];
    __shared__ float w_s[32 * 32];
    int b = blockIdx.z, y = blockIdx.y, oc0 = blockIdx.x * 32;
    int t = threadIdx.x;
    int co = (t >> 4) * 4;    // 0..28
    int x0 = (t & 15) * 4;
    float acc[4][4] = {};
    for (int ic0 = 0; ic0 < inC; ic0 += 32) {
        for (int idx = t; idx < 2048; idx += 128) {
            int xx = idx & 63; int ic = idx >> 6;
            float v = in[((size_t)(b * inC + ic0 + ic) * 64 + y) * 64 + xx];
            if (RELU_IN) v = fmaxf(v, 0.f);
            in_s[ic * 64 + xx] = v;
        }
        for (int idx = t; idx < 1024; idx += 128) {
            int j = idx & 31; int ic = idx >> 5;
            w_s[idx] = wT[(size_t)(ic0 + ic) * wStride + oc0 + j];
        }
        __syncthreads();
        #pragma unroll 8
        for (int ic = 0; ic < 32; ic++) {
            float4 iv = *(const float4*)&in_s[ic * 64 + x0];
            float4 wv = *(const float4*)&w_s[ic * 32 + co];
            const float* ip = (const float*)&iv;
            const float* wp = (const float*)&wv;
            #pragma unroll
            for (int cc = 0; cc < 4; cc++)
                #pragma unroll
                for (int j = 0; j < 4; j++) acc[cc][j] += wp[cc] * ip[j];
        }
        __syncthreads();
    }
    #pragma unroll
    for (int cc = 0; cc < 4; cc++) {
        int oc = oc0 + co + cc;
        if (oc < outC) {
            float4 o;
            o.x = acc[cc][0]; o.y = acc[cc][1]; o.z = acc[cc][2]; o.w = acc[cc][3];
            if (RELU_OUT) {
                o.x = fmaxf(o.x, 0.f); o.y = fmaxf(o.y, 0.f);
                o.z = fmaxf(o.z, 0.f); o.w = fmaxf(o.w, 0.f);
            }
            *(float4*)&out[((size_t)(b * outC + oc) * 64 + y) * 64 + x0] = o;
        }
    }
}

__device__ __forceinline__ float softplusf_(float z) {
    return fmaxf(z, 0.f) + log1pf(expf(-fabsf(z)));
}
__device__ __forceinline__ float sigmoidf_(float z) {
    return 1.f / (1.f + expf(-z));
}

// DMOL: grid 256 (b*16 + ygroup), block 256 (wave per row). atomicAdd partials to out[b].
__global__ __launch_bounds__(256) void k_dmol(const float* __restrict__ x,
                                              const float* __restrict__ P,
                                              float* __restrict__ out) {
    int b = blockIdx.x >> 4, yg = blockIdx.x & 15;
    int t = threadIdx.x;
    int y = yg * 4 + (t >> 6), xx = t & 63;
    size_t pos = (size_t)y * 64 + xx;
    const float* pb = P + (size_t)b * 100 * 4096 + pos;
    float xs[3];
    #pragma unroll
    for (int c = 0; c < 3; c++) xs[c] = x[((size_t)(b * 3 + c)) * 4096 + pos];

    float lg[10];
    #pragma unroll
    for (int m = 0; m < 10; m++) lg[m] = pb[(size_t)m * 4096];
    float mx = lg[0];
    #pragma unroll
    for (int m = 1; m < 10; m++) mx = fmaxf(mx, lg[m]);
    float se = 0.f;
    #pragma unroll
    for (int m = 0; m < 10; m++) se += expf(lg[m] - mx);
    float lse = mx + logf(se);

    const float LOG127P5 = 4.8481163504f;   // ln(127.5)
    float lpm[10];
    #pragma unroll
    for (int m = 0; m < 10; m++) {
        float sum = lg[m] - lse;
        float mean0 = pb[(size_t)(10 + 0 * 30 + m) * 4096];
        float mean1 = pb[(size_t)(10 + 1 * 30 + m) * 4096];
        float mean2 = pb[(size_t)(10 + 2 * 30 + m) * 4096];
        float ls0 = fmaxf(pb[(size_t)(10 + 0 * 30 + 10 + m) * 4096], -7.f);
        float ls1 = fmaxf(pb[(size_t)(10 + 1 * 30 + 10 + m) * 4096], -7.f);
        float ls2 = fmaxf(pb[(size_t)(10 + 2 * 30 + 10 + m) * 4096], -7.f);
        float c0 = tanhf(pb[(size_t)(10 + 0 * 30 + 20 + m) * 4096]);
        float c1 = tanhf(pb[(size_t)(10 + 1 * 30 + 20 + m) * 4096]);
        float c2 = tanhf(pb[(size_t)(10 + 2 * 30 + 20 + m) * 4096]);
        float mu[3], lsv[3];
        mu[0] = mean0;
        mu[1] = mean1 + c0 * xs[0];
        mu[2] = mean2 + c1 * xs[0] + c2 * xs[1];
        lsv[0] = ls0; lsv[1] = ls1; lsv[2] = ls2;
        #pragma unroll
        for (int ci = 0; ci < 3; ci++) {
            float cent = xs[ci] - mu[ci];
            float inv = expf(-lsv[ci]);
            float plus_in = inv * (cent + 1.f / 255.f);
            float min_in = inv * (cent - 1.f / 255.f);
            float cdf_delta = sigmoidf_(plus_in) - sigmoidf_(min_in);
            float log_cdf_plus = plus_in - softplusf_(plus_in);
            float log_om_cdf = -softplusf_(min_in);
            float mid = inv * cent;
            float log_pdf_mid = mid - lsv[ci] - 2.f * softplusf_(mid);
            float lpi = (cdf_delta > 1e-5f) ? logf(fmaxf(cdf_delta, 1e-12f))
                                            : (log_pdf_mid - LOG127P5);
            float lpc = (xs[ci] < -0.999f) ? log_cdf_plus
                       : ((xs[ci] > 0.999f) ? log_om_cdf : lpi);
            sum += lpc;
        }
        lpm[m] = sum;
    }
    float mx2 = lpm[0];
    #pragma unroll
    for (int m = 1; m < 10; m++) mx2 = fmaxf(mx2, lpm[m]);
    float se2 = 0.f;
    #pragma unroll
    for (int m = 0; m < 10; m++) se2 += expf(lpm[m] - mx2);
    float lp = mx2 + logf(se2);

    #pragma unroll
    for (int off = 32; off > 0; off >>= 1) lp += __shfl_down(lp, off, 64);
    __shared__ float red[4];
    if ((t & 63) == 0) red[t >> 6] = lp;
    __syncthreads();
    if (t == 0) atomicAdd(&out[b], red[0] + red[1] + red[2] + red[3]);
}

extern "C" void kernel_launch(void* const* d_in, const int* in_sizes, int n_in,
                              void* d_out, int out_size, void* d_ws, size_t ws_size,
                              hipStream_t stream) {
    const float* samples = (const float*)d_in[0];
    const float* w_in    = (const float*)d_in[1];
    const float* w_blk   = (const float*)d_in[2];
    const float* w_out1  = (const float*)d_in[3];
    const float* w_out2  = (const float*)d_in[4];
    char* ws = (char*)d_ws;
    float* X    = (float*)(ws + X_OFF);
    float* WTIN = (float*)(ws + WTIN_OFF);
    float* WT1  = (float*)(ws + WT1_OFF);
    float* WT2  = (float*)(ws + WT2_OFF);
    float* WTB  = (float*)(ws + WTB_OFF);
    float* H0   = (float*)(ws + H0_OFF);
    float* H1   = (float*)(ws + H1_OFF);
    float* fout = (float*)d_out;

    k_prep<<<768, 256, 0, stream>>>(samples, X, 16 * 3 * 4096);
    k_twtb<<<5000, 256, 0, stream>>>(w_blk, WTB);
    k_twtin<<<45, 256, 0, stream>>>(w_in, WTIN);
    k_tw1<<<100, 256, 0, stream>>>(w_out1, WT1);
    k_tw2<<<80, 256, 0, stream>>>(w_out2, WT2);

    k_convin<<<dim3(10, 64, 16), 256, 0, stream>>>(X, WTIN, H0);

    float* a = H0; float* bq = H1;
    for (int i = 0; i < 5; i++) {
        k_blk<<<dim3(5, 64, 16), 256, 0, stream>>>(a, bq, WTB + (size_t)i * 5 * 160 * 320);
        float* tmp = a; a = bq; bq = tmp;
    }
    // final h is in `a` (= H1 after 5 iters); bq = H0
    k_c1x1<true, true><<<dim3(5, 64, 16), 128, 0, stream>>>(a, bq, WT1, 160, 160, 160);
    // params -> write into H1 region (a); reads bq (H0)
    float* Pp = a;
    k_c1x1<false, false><<<dim3(4, 64, 16), 128, 0, stream>>>(bq, Pp, WT2, 160, 128, 100);

    hipMemsetAsync(d_out, 0, (size_t)out_size * sizeof(float), stream);
    k_dmol<<<256, 256, 0, stream>>>(X, Pp, fout);
}

// Round 2
// 706.157 us; speedup vs baseline: 6.6928x; 6.6928x over previous
//
#include <hip/hip_runtime.h>
#include <math.h>

// ---------------------------------------------------------------------------
// PixelCNN (5 gated residual blocks) + DMOL logprob.
// Round 2: gated block conv -> bf16 MFMA implicit GEMM (M=320, N=64/row, K=800)
//   - hT: relu(h) in bf16, channel-last [b][y][x][160] for contiguous B-frags
//   - weights pre-packed to A-fragment order [kt25][oc320][icl32] bf16,
//     A-frags loaded straight from global (L2-hot), no K-loop barriers
//   - gating in-register (wave owns a-channels and their b-partners)
// ---------------------------------------------------------------------------

using short8  = __attribute__((ext_vector_type(8))) short;
using short4v = __attribute__((ext_vector_type(4))) short;
using f32x4   = __attribute__((ext_vector_type(4))) float;

__device__ __forceinline__ short f2bf(float f) {
    union { float f; unsigned u; } v; v.f = f;
    unsigned r = (v.u + 0x7fffu + ((v.u >> 16) & 1u)) >> 16;
    return (short)r;
}

// workspace layout (bytes), all 16B-aligned
static constexpr size_t X_OFF    = 0;                   // 16*3*4096*4    = 786432
static constexpr size_t WTIN_OFF = 786432;              // 24*3*160*4     = 46080
static constexpr size_t WT1_OFF  = 832512;              // 160*160*4      = 102400
static constexpr size_t WT2_OFF  = 934912;              // 160*128*4      = 81920
static constexpr size_t WPB_OFF  = 1016832;             // 5*25*320*32*2  = 2560000
static constexpr size_t H0_OFF   = 3576832;             // 41943040
static constexpr size_t H1_OFF   = 45519872;            // 41943040
static constexpr size_t HT0_OFF  = 87462912;            // 16*4096*160*2  = 20971520
static constexpr size_t HT1_OFF  = 108434432;           // 20971520 (end ~129.4 MB)

__global__ void k_prep(const float* __restrict__ s, float* __restrict__ x, int n) {
    int i = blockIdx.x * 256 + threadIdx.x;
    if (i < n) x[i] = 2.f * s[i] - 1.f;
}

// w_blk (5,320,160,3,3) -> bf16 wP[i][kt=tap*5+ic0/32][oc320][icl32]
__global__ void k_twb(const float* __restrict__ w, short* __restrict__ wP) {
    int idx = blockIdx.x * 256 + threadIdx.x;
    if (idx >= 5 * 25 * 320 * 32) return;
    int icl = idx & 31;
    int oc  = (idx >> 5) % 320;
    int kt  = ((idx >> 5) / 320) % 25;
    int i   = idx / (25 * 320 * 32);
    int tap = kt / 5, ic = (kt % 5) * 32 + icl;
    const int ky[5] = {0,0,0,1,1}, kx[5] = {0,1,2,0,1};
    float v = w[(((size_t)(i * 320 + oc) * 160 + ic) * 3 + ky[tap]) * 3 + kx[tap]];
    wP[idx] = f2bf(v);
}

// w_in (160,3,7,7) -> wT[tap24][ic3][oc160], mask-A taps
__global__ void k_twtin(const float* __restrict__ w, float* __restrict__ wT) {
    int idx = blockIdx.x * 256 + threadIdx.x;
    if (idx >= 24 * 3 * 160) return;
    int oc = idx % 160; int t2 = idx / 160;
    int ic = t2 % 3; int tap = t2 / 3;
    int ky, kx;
    if (tap < 21) { ky = tap / 7; kx = tap % 7; } else { ky = 3; kx = tap - 21; }
    wT[idx] = w[((oc * 3 + ic) * 7 + ky) * 7 + kx];
}

__global__ void k_tw1(const float* __restrict__ w, float* __restrict__ wT) { // [ic][oc] 160x160
    int idx = blockIdx.x * 256 + threadIdx.x;
    if (idx >= 160 * 160) return;
    int oc = idx % 160, ic = idx / 160;
    wT[idx] = w[oc * 160 + ic];
}

__global__ void k_tw2(const float* __restrict__ w, float* __restrict__ wT) { // [ic][128] zero-padded
    int idx = blockIdx.x * 256 + threadIdx.x;
    if (idx >= 160 * 128) return;
    int oc = idx % 128, ic = idx / 128;
    wT[idx] = (oc < 100) ? w[oc * 160 + ic] : 0.f;
}

// masked 7x7 input conv: grid (10, 64, 16), block 256. Each WG: 16 oc x 64 x.
__global__ __launch_bounds__(256) void k_convin(const float* __restrict__ x,
                                                const float* __restrict__ wT,
                                                float* __restrict__ h) {
    __shared__ float xin_s[3 * 4 * 72];
    __shared__ float w_s[24 * 3 * 16];
    int b = blockIdx.z, y = blockIdx.y, oc0 = blockIdx.x * 16;
    int t = threadIdx.x;
    for (int idx = t; idx < 3 * 4 * 70; idx += 256) {
        int col = idx % 70; int r = (idx / 70) % 4; int ic = idx / 280;
        int xg = col - 3, yg = y + r - 3;
        float v = 0.f;
        if (xg >= 0 && xg < 64 && yg >= 0)
            v = x[((size_t)(b * 3 + ic) * 64 + yg) * 64 + xg];
        xin_s[(ic * 4 + r) * 72 + col] = v;
    }
    for (int idx = t; idx < 24 * 3 * 16; idx += 256) {
        int j = idx % 16; int ic = (idx / 16) % 3; int tap = idx / 48;
        w_s[idx] = wT[(tap * 3 + ic) * 160 + oc0 + j];
    }
    __syncthreads();
    int ch = t >> 4;
    int x0 = (t & 15) * 4;
    float acc[4] = {0.f, 0.f, 0.f, 0.f};
    #pragma unroll
    for (int ic = 0; ic < 3; ic++) {
        #pragma unroll
        for (int r = 0; r < 4; r++) {
            const float* rp = &xin_s[(ic * 4 + r) * 72 + x0];
            float v[10];
            *(float4*)&v[0] = *(const float4*)&rp[0];
            *(float4*)&v[4] = *(const float4*)&rp[4];
            *(float2*)&v[8] = *(const float2*)&rp[8];
            const int nd = (r < 3) ? 7 : 3;
            #pragma unroll
            for (int d = 0; d < 7; d++) {
                if (d < nd) {
                    int tap = (r < 3) ? (r * 7 + d) : (21 + d);
                    float wv = w_s[(tap * 3 + ic) * 16 + ch];
                    #pragma unroll
                    for (int j = 0; j < 4; j++) acc[j] += wv * v[d + j];
                }
            }
        }
    }
    size_t off = ((size_t)(b * 160 + oc0 + ch)) * 4096 + (size_t)y * 64 + x0;
    float4 o; o.x = acc[0]; o.y = acc[1]; o.z = acc[2]; o.w = acc[3];
    *(float4*)&h[off] = o;
}

// h fp32 [b][c][y][x] -> hT bf16 relu'd channel-last [b][y][x][160]
__global__ __launch_bounds__(256) void k_h2hT(const float* __restrict__ h, short* __restrict__ hT) {
    __shared__ short l_s[64 * 168];
    int y = blockIdx.x, b = blockIdx.y;
    int t = threadIdx.x;
    for (int idx = t; idx < 10240; idx += 256) {
        int c = idx >> 6, xx = idx & 63;
        float v = fmaxf(h[((size_t)(b * 160 + c) * 64 + y) * 64 + xx], 0.f);
        l_s[xx * 168 + c] = f2bf(v);
    }
    __syncthreads();
    for (int j = t; j < 2560; j += 256) {
        int xx = j / 40, k4 = (j % 40) * 4;
        *(short4v*)&hT[(((size_t)(b * 64 + y) * 64 + xx) * 160) + k4] =
            *(const short4v*)&l_s[xx * 168 + k4];
    }
}

// MFMA gated block conv. grid (64, 16) = (y, b), block 320 (5 waves).
// Wave w: a-channels 32w..32w+31 and b-partners 160+32w.. ; N = 64 px (row y).
__global__ __launch_bounds__(320) void k_blk(const float* __restrict__ hin,
                                             float* __restrict__ hout,
                                             const short* __restrict__ hTin,
                                             short* __restrict__ hTout,
                                             const short* __restrict__ wP) {
    __shared__ short in_s[2 * 66 * 168];   // [row2][x 0..65][ic pad168]  44352 B
    int y = blockIdx.x, b = blockIdx.y;
    int t = threadIdx.x;
    // stage rows y-1, y of hTin (relu'd bf16) with x halo
    for (int i = t; i < 2640; i += 320) {
        int c8 = i % 20; int x_l = (i / 20) % 66; int r = i / 1320;
        int x_g = x_l - 1, y_g = y + r - 1;
        short8 v = {};
        if (x_g >= 0 && x_g < 64 && y_g >= 0)
            v = *(const short8*)&hTin[(((size_t)(b * 64 + y_g) * 64 + x_g) * 160) + c8 * 8];
        *(short8*)&in_s[(r * 66 + x_l) * 168 + c8 * 8] = v;
    }
    __syncthreads();

    int lane = t & 63, w = t >> 6;
    int lx = lane & 15, q = lane >> 4;
    int ocb0 = 32 * w;
    f32x4 acc[4][4] = {};
    const short* wl = wP + lx * 32 + q * 8;
    const int dxs[5] = {-1, 0, 1, -1, 0};
    const int rws[5] = {0, 0, 0, 1, 1};
    #pragma unroll
    for (int tap = 0; tap < 5; ++tap) {
        int rb = (rws[tap] * 66 + 1 + dxs[tap] + lx) * 168 + q * 8;
        #pragma unroll
        for (int kt5 = 0; kt5 < 5; ++kt5) {
            int ic0 = kt5 * 32;
            const short* wk = wl + (tap * 5 + kt5) * 10240;
            short8 aF[4], bF[4];
            aF[0] = *(const short8*)(wk + (ocb0)*32);
            aF[1] = *(const short8*)(wk + (ocb0 + 16) * 32);
            aF[2] = *(const short8*)(wk + (160 + ocb0) * 32);
            aF[3] = *(const short8*)(wk + (160 + ocb0 + 16) * 32);
            #pragma unroll
            for (int nt = 0; nt < 4; ++nt)
                bF[nt] = *(const short8*)&in_s[rb + nt * 16 * 168 + ic0];
            #pragma unroll
            for (int mt = 0; mt < 4; ++mt)
                #pragma unroll
                for (int nt = 0; nt < 4; ++nt)
                    acc[mt][nt] = __builtin_amdgcn_mfma_f32_16x16x32_bf16(
                        aF[mt], bF[nt], acc[mt][nt], 0, 0, 0);
        }
    }
    __syncthreads();
    // gating epilogue: a = acc[0..1], b = acc[2..3]; in-register pairing
    #pragma unroll
    for (int mt = 0; mt < 2; ++mt) {
        #pragma unroll
        for (int nt = 0; nt < 4; ++nt) {
            #pragma unroll
            for (int r = 0; r < 4; ++r) {
                int c = ocb0 + mt * 16 + q * 4 + r;
                int xx = nt * 16 + lx;
                float av = acc[mt][nt][r];
                float bv = acc[mt + 2][nt][r];
                size_t off = ((size_t)(b * 160 + c) * 64 + y) * 64 + xx;
                float hn = hin[off] + tanhf(av) * (1.f / (1.f + expf(-bv)));
                hout[off] = hn;
                in_s[xx * 168 + c] = f2bf(fmaxf(hn, 0.f));
            }
        }
    }
    __syncthreads();
    // coalesced write of relu'd bf16 channel-last row
    for (int j = t; j < 2560; j += 320) {
        int xx = j / 40, k4 = (j % 40) * 4;
        *(short4v*)&hTout[(((size_t)(b * 64 + y) * 64 + xx) * 160) + k4] =
            *(const short4v*)&in_s[xx * 168 + k4];
    }
}

// 1x1 conv: grid (ocGroups, 64, 16), block 128. WG: 32 oc x 64 x.
template <bool RELU_IN, bool RELU_OUT>
__global__ __launch_bounds__(128) void k_c1x1(const float* __restrict__ in,
                                              float* __restrict__ out,
                                              const float* __restrict__ wT,
                                              int inC, int wStride, int outC) {
    __shared__ float in_s[32 * 64];
    __shared__ float w_s[32 * 32];
    int b = blockIdx.z, y = blockIdx.y, oc0 = blockIdx.x * 32;
    int t = threadIdx.x;
    int co = (t >> 4) * 4;
    int x0 = (t & 15) * 4;
    float acc[4][4] = {};
    for (int ic0 = 0; ic0 < inC; ic0 += 32) {
        for (int idx = t; idx < 2048; idx += 128) {
            int xx = idx & 63; int ic = idx >> 6;
            float v = in[((size_t)(b * inC + ic0 + ic) * 64 + y) * 64 + xx];
            if (RELU_IN) v = fmaxf(v, 0.f);
            in_s[ic * 64 + xx] = v;
        }
        for (int idx = t; idx < 1024; idx += 128) {
            int j = idx & 31; int ic = idx >> 5;
            w_s[idx] = wT[(size_t)(ic0 + ic) * wStride + oc0 + j];
        }
        __syncthreads();
        #pragma unroll 8
        for (int ic = 0; ic < 32; ic++) {
            float4 iv = *(const float4*)&in_s[ic * 64 + x0];
            float4 wv = *(const float4*)&w_s[ic * 32 + co];
            const float* ip = (const float*)&iv;
            const float* wp = (const float*)&wv;
            #pragma unroll
            for (int cc = 0; cc < 4; cc++)
                #pragma unroll
                for (int j = 0; j < 4; j++) acc[cc][j] += wp[cc] * ip[j];
        }
        __syncthreads();
    }
    #pragma unroll
    for (int cc = 0; cc < 4; cc++) {
        int oc = oc0 + co + cc;
        if (oc < outC) {
            float4 o;
            o.x = acc[cc][0]; o.y = acc[cc][1]; o.z = acc[cc][2]; o.w = acc[cc][3];
            if (RELU_OUT) {
                o.x = fmaxf(o.x, 0.f); o.y = fmaxf(o.y, 0.f);
                o.z = fmaxf(o.z, 0.f); o.w = fmaxf(o.w, 0.f);
            }
            *(float4*)&out[((size_t)(b * outC + oc) * 64 + y) * 64 + x0] = o;
        }
    }
}

__device__ __forceinline__ float softplusf_(float z) {
    return fmaxf(z, 0.f) + log1pf(expf(-fabsf(z)));
}
__device__ __forceinline__ float sigmoidf_(float z) {
    return 1.f / (1.f + expf(-z));
}

// DMOL: grid 256 (b*16 + ygroup), block 256. atomicAdd partials to out[b].
__global__ __launch_bounds__(256) void k_dmol(const float* __restrict__ x,
                                              const float* __restrict__ P,
                                              float* __restrict__ out) {
    int b = blockIdx.x >> 4, yg = blockIdx.x & 15;
    int t = threadIdx.x;
    int y = yg * 4 + (t >> 6), xx = t & 63;
    size_t pos = (size_t)y * 64 + xx;
    const float* pb = P + (size_t)b * 100 * 4096 + pos;
    float xs[3];
    #pragma unroll
    for (int c = 0; c < 3; c++) xs[c] = x[((size_t)(b * 3 + c)) * 4096 + pos];

    float lg[10];
    #pragma unroll
    for (int m = 0; m < 10; m++) lg[m] = pb[(size_t)m * 4096];
    float mx = lg[0];
    #pragma unroll
    for (int m = 1; m < 10; m++) mx = fmaxf(mx, lg[m]);
    float se = 0.f;
    #pragma unroll
    for (int m = 0; m < 10; m++) se += expf(lg[m] - mx);
    float lse = mx + logf(se);

    const float LOG127P5 = 4.8481163504f;
    float lpm[10];
    #pragma unroll
    for (int m = 0; m < 10; m++) {
        float sum = lg[m] - lse;
        float mean0 = pb[(size_t)(10 + 0 * 30 + m) * 4096];
        float mean1 = pb[(size_t)(10 + 1 * 30 + m) * 4096];
        float mean2 = pb[(size_t)(10 + 2 * 30 + m) * 4096];
        float ls0 = fmaxf(pb[(size_t)(10 + 0 * 30 + 10 + m) * 4096], -7.f);
        float ls1 = fmaxf(pb[(size_t)(10 + 1 * 30 + 10 + m) * 4096], -7.f);
        float ls2 = fmaxf(pb[(size_t)(10 + 2 * 30 + 10 + m) * 4096], -7.f);
        float c0 = tanhf(pb[(size_t)(10 + 0 * 30 + 20 + m) * 4096]);
        float c1 = tanhf(pb[(size_t)(10 + 1 * 30 + 20 + m) * 4096]);
        float c2 = tanhf(pb[(size_t)(10 + 2 * 30 + 20 + m) * 4096]);
        float mu[3], lsv[3];
        mu[0] = mean0;
        mu[1] = mean1 + c0 * xs[0];
        mu[2] = mean2 + c1 * xs[0] + c2 * xs[1];
        lsv[0] = ls0; lsv[1] = ls1; lsv[2] = ls2;
        #pragma unroll
        for (int ci = 0; ci < 3; ci++) {
            float cent = xs[ci] - mu[ci];
            float inv = expf(-lsv[ci]);
            float plus_in = inv * (cent + 1.f / 255.f);
            float min_in = inv * (cent - 1.f / 255.f);
            float cdf_delta = sigmoidf_(plus_in) - sigmoidf_(min_in);
            float log_cdf_plus = plus_in - softplusf_(plus_in);
            float log_om_cdf = -softplusf_(min_in);
            float mid = inv * cent;
            float log_pdf_mid = mid - lsv[ci] - 2.f * softplusf_(mid);
            float lpi = (cdf_delta > 1e-5f) ? logf(fmaxf(cdf_delta, 1e-12f))
                                            : (log_pdf_mid - LOG127P5);
            float lpc = (xs[ci] < -0.999f) ? log_cdf_plus
                       : ((xs[ci] > 0.999f) ? log_om_cdf : lpi);
            sum += lpc;
        }
        lpm[m] = sum;
    }
    float mx2 = lpm[0];
    #pragma unroll
    for (int m = 1; m < 10; m++) mx2 = fmaxf(mx2, lpm[m]);
    float se2 = 0.f;
    #pragma unroll
    for (int m = 0; m < 10; m++) se2 += expf(lpm[m] - mx2);
    float lp = mx2 + logf(se2);

    #pragma unroll
    for (int off = 32; off > 0; off >>= 1) lp += __shfl_down(lp, off, 64);
    __shared__ float red[4];
    if ((t & 63) == 0) red[t >> 6] = lp;
    __syncthreads();
    if (t == 0) atomicAdd(&out[b], red[0] + red[1] + red[2] + red[3]);
}

extern "C" void kernel_launch(void* const* d_in, const int* in_sizes, int n_in,
                              void* d_out, int out_size, void* d_ws, size_t ws_size,
                              hipStream_t stream) {
    const float* samples = (const float*)d_in[0];
    const float* w_in    = (const float*)d_in[1];
    const float* w_blk   = (const float*)d_in[2];
    const float* w_out1  = (const float*)d_in[3];
    const float* w_out2  = (const float*)d_in[4];
    char* ws = (char*)d_ws;
    float* X    = (float*)(ws + X_OFF);
    float* WTIN = (float*)(ws + WTIN_OFF);
    float* WT1  = (float*)(ws + WT1_OFF);
    float* WT2  = (float*)(ws + WT2_OFF);
    short* WPB  = (short*)(ws + WPB_OFF);
    float* H0   = (float*)(ws + H0_OFF);
    float* H1   = (float*)(ws + H1_OFF);
    short* HT0  = (short*)(ws + HT0_OFF);
    short* HT1  = (short*)(ws + HT1_OFF);
    float* fout = (float*)d_out;

    k_prep<<<768, 256, 0, stream>>>(samples, X, 16 * 3 * 4096);
    k_twb<<<5000, 256, 0, stream>>>(w_blk, WPB);
    k_twtin<<<45, 256, 0, stream>>>(w_in, WTIN);
    k_tw1<<<100, 256, 0, stream>>>(w_out1, WT1);
    k_tw2<<<80, 256, 0, stream>>>(w_out2, WT2);

    k_convin<<<dim3(10, 64, 16), 256, 0, stream>>>(X, WTIN, H0);
    k_h2hT<<<dim3(64, 16), 256, 0, stream>>>(H0, HT0);

    float* a = H0; float* bq = H1;
    short* ta = HT0; short* tb = HT1;
    for (int i = 0; i < 5; i++) {
        k_blk<<<dim3(64, 16), 320, 0, stream>>>(a, bq, ta, tb, WPB + (size_t)i * 25 * 320 * 32);
        float* tmp = a; a = bq; bq = tmp;
        short* tt = ta; ta = tb; tb = tt;
    }
    // final h is in `a` (= H1 after 5 iters); bq = H0
    k_c1x1<true, true><<<dim3(5, 64, 16), 128, 0, stream>>>(a, bq, WT1, 160, 160, 160);
    float* Pp = a;
    k_c1x1<false, false><<<dim3(4, 64, 16), 128, 0, stream>>>(bq, Pp, WT2, 160, 128, 100);

    hipMemsetAsync(d_out, 0, (size_t)out_size * sizeof(float), stream);
    k_dmol<<<256, 256, 0, stream>>>(X, Pp, fout);
}

// Round 3
// 518.636 us; speedup vs baseline: 9.1126x; 1.3616x over previous
//
#include <hip/hip_runtime.h>
#include <math.h>

// ---------------------------------------------------------------------------
// PixelCNN (5 gated residual blocks) + DMOL logprob.  Round 3:
//   - h lives ONLY as fp32 channel-last [b][y][x][160] (single stream)
//   - k_blk: MFMA 16x16x32, stages relu+bf16 in LDS from h-CL, in-register
//     gating, float4 residual read/modify/write (no hT buffers, no tail sync)
//   - k_convin: MFMA via LDS im2col (K=72 pad 96), writes h-CL
//   - k_head: fused conv1x1+relu+conv1x1+DMOL per row, atomicAdd to out
// ---------------------------------------------------------------------------

using short8  = __attribute__((ext_vector_type(8))) short;
using short4v = __attribute__((ext_vector_type(4))) short;
using f32x4   = __attribute__((ext_vector_type(4))) float;

__device__ __forceinline__ short f2bf(float f) {
    union { float f; unsigned u; } v; v.f = f;
    unsigned r = (v.u + 0x7fffu + ((v.u >> 16) & 1u)) >> 16;
    return (short)r;
}

__device__ __forceinline__ short8 pack8_relu(float4 a, float4 b) {
    short8 r;
    r[0] = f2bf(fmaxf(a.x, 0.f)); r[1] = f2bf(fmaxf(a.y, 0.f));
    r[2] = f2bf(fmaxf(a.z, 0.f)); r[3] = f2bf(fmaxf(a.w, 0.f));
    r[4] = f2bf(fmaxf(b.x, 0.f)); r[5] = f2bf(fmaxf(b.y, 0.f));
    r[6] = f2bf(fmaxf(b.z, 0.f)); r[7] = f2bf(fmaxf(b.w, 0.f));
    return r;
}

// workspace layout (bytes), 16B-aligned
static constexpr size_t X_OFF    = 0;             // 16*3*4096*4    = 786432
static constexpr size_t WINP_OFF = 786432;        // 3*160*32*2     = 30720
static constexpr size_t W1P_OFF  = 817152;        // 5*160*32*2     = 51200
static constexpr size_t W2P_OFF  = 868352;        // 5*160*32*2     = 51200
static constexpr size_t WPB_OFF  = 919552;        // 5*25*320*32*2  = 2560000
static constexpr size_t HA_OFF   = 3479552;       // 16*4096*160*4  = 41943040
static constexpr size_t HB_OFF   = 45422592;      // 41943040  (end ~87.4 MB)

__global__ void k_prep(const float* __restrict__ s, float* __restrict__ x, int n) {
    int i = blockIdx.x * 256 + threadIdx.x;
    if (i < n) x[i] = 2.f * s[i] - 1.f;
}

// w_blk (5,320,160,3,3) -> bf16 wP[i][kt=tap*5+icb][oc320][icl32]
__global__ void k_twb(const float* __restrict__ w, short* __restrict__ wP) {
    int idx = blockIdx.x * 256 + threadIdx.x;
    if (idx >= 5 * 25 * 320 * 32) return;
    int icl = idx & 31;
    int oc  = (idx >> 5) % 320;
    int kt  = ((idx >> 5) / 320) % 25;
    int i   = idx / (25 * 320 * 32);
    int tap = kt / 5, ic = (kt % 5) * 32 + icl;
    const int ky[5] = {0,0,0,1,1}, kx[5] = {0,1,2,0,1};
    float v = w[(((size_t)(i * 320 + oc) * 160 + ic) * 3 + ky[tap]) * 3 + kx[tap]];
    wP[idx] = f2bf(v);
}

// w_in (160,3,7,7) -> WINP[kc3][oc160][icl32], k=tap*3+ic over 24 mask-A taps, pad to 96
__global__ void k_twin(const float* __restrict__ w, short* __restrict__ wP) {
    int idx = blockIdx.x * 256 + threadIdx.x;
    if (idx >= 3 * 160 * 32) return;
    int icl = idx & 31;
    int oc  = (idx >> 5) % 160;
    int kc  = idx / 5120;
    int k = kc * 32 + icl;
    short v = 0;
    if (k < 72) {
        int tap = k / 3, ic = k % 3;
        int ky = (tap < 21) ? tap / 7 : 3;
        int kx = (tap < 21) ? tap % 7 : tap - 21;
        v = f2bf(w[((oc * 3 + ic) * 7 + ky) * 7 + kx]);
    }
    wP[idx] = v;
}

// w_out1 (160,160,1,1) -> W1P[kc5][oc160][icl32]
__global__ void k_tw1(const float* __restrict__ w, short* __restrict__ wP) {
    int idx = blockIdx.x * 256 + threadIdx.x;
    if (idx >= 5 * 160 * 32) return;
    int icl = idx & 31;
    int oc  = (idx >> 5) % 160;
    int kc  = idx / 5120;
    wP[idx] = f2bf(w[oc * 160 + kc * 32 + icl]);
}

// w_out2 (100,160,1,1) -> W2P[kc5][oc160 pad][icl32]
__global__ void k_tw2(const float* __restrict__ w, short* __restrict__ wP) {
    int idx = blockIdx.x * 256 + threadIdx.x;
    if (idx >= 5 * 160 * 32) return;
    int icl = idx & 31;
    int oc  = (idx >> 5) % 160;
    int kc  = idx / 5120;
    wP[idx] = (oc < 100) ? f2bf(w[oc * 160 + kc * 32 + icl]) : (short)0;
}

// masked 7x7 input conv, MFMA. grid (64,16) = (y,b), block 320 (5 waves).
// M=160 (2 m-tiles/wave), N=64 (4 n-tiles), K=72 pad 96 (3 kc). Writes h fp32 CL.
__global__ __launch_bounds__(320) void k_convin(const float* __restrict__ X,
                                                const short* __restrict__ WINP,
                                                float* __restrict__ hout) {
    __shared__ float xls[3 * 4 * 72];   // [ic][r=ky][col], col = xg+3 (0..69)
    __shared__ short Bls[64 * 104];     // [px][k pad104]
    int y = blockIdx.x, b = blockIdx.y;
    int t = threadIdx.x;
    for (int i = t; i < 840; i += 320) {
        int col = i % 70; int r = (i / 70) % 4; int ic = i / 280;
        int xg = col - 3, yg = y + r - 3;
        float v = 0.f;
        if (xg >= 0 && xg < 64 && yg >= 0)
            v = X[((size_t)(b * 3 + ic) * 64 + yg) * 64 + xg];
        xls[(ic * 4 + r) * 72 + col] = v;
    }
    __syncthreads();
    for (int i = t; i < 6144; i += 320) {
        int k = i % 96; int px = i / 96;
        short v = 0;
        if (k < 72) {
            int tap = k / 3, ic = k % 3;
            int ky = (tap < 21) ? tap / 7 : 3;
            int kx = (tap < 21) ? tap % 7 : tap - 21;
            v = f2bf(xls[(ic * 4 + ky) * 72 + px + kx]);
        }
        Bls[px * 104 + k] = v;
    }
    __syncthreads();
    int lane = t & 63, w = t >> 6;
    int lx = lane & 15, q = lane >> 4;
    f32x4 acc[2][4] = {};
    const short* wl = WINP + lx * 32 + q * 8;
    #pragma unroll
    for (int kc = 0; kc < 3; ++kc) {
        short8 aF[2], bF[4];
        aF[0] = *(const short8*)(wl + (kc * 160 + 32 * w) * 32);
        aF[1] = *(const short8*)(wl + (kc * 160 + 32 * w + 16) * 32);
        #pragma unroll
        for (int nt = 0; nt < 4; ++nt)
            bF[nt] = *(const short8*)&Bls[(nt * 16 + lx) * 104 + kc * 32 + q * 8];
        #pragma unroll
        for (int mt = 0; mt < 2; ++mt)
            #pragma unroll
            for (int nt = 0; nt < 4; ++nt)
                acc[mt][nt] = __builtin_amdgcn_mfma_f32_16x16x32_bf16(
                    aF[mt], bF[nt], acc[mt][nt], 0, 0, 0);
    }
    size_t rowbase = ((size_t)(b * 64 + y)) * 64 * 160;
    #pragma unroll
    for (int mt = 0; mt < 2; ++mt) {
        int c0 = 32 * w + mt * 16 + q * 4;
        #pragma unroll
        for (int nt = 0; nt < 4; ++nt) {
            int px = nt * 16 + lx;
            float4 o;
            o.x = acc[mt][nt][0]; o.y = acc[mt][nt][1];
            o.z = acc[mt][nt][2]; o.w = acc[mt][nt][3];
            *(float4*)&hout[rowbase + (size_t)px * 160 + c0] = o;
        }
    }
}

// MFMA gated block conv on h fp32 CL. grid (64,16) = (y,b), block 320 (5 waves).
// Wave w: a-channels 32w..32w+31 (m-tiles 0,1), b-partners 160+32w.. (m-tiles 2,3).
__global__ __launch_bounds__(320, 4) void k_blk(const float* __restrict__ hin,
                                                float* __restrict__ hout,
                                                const short* __restrict__ wP) {
    __shared__ short in_s[2 * 66 * 168];   // [r][x 0..65][ic pad168] = 44352 B
    int y = blockIdx.x, b = blockIdx.y;
    int t = threadIdx.x;
    // stage rows y-1, y: relu(h) -> bf16 (x halo, zero-pad OOB)
    for (int i = t; i < 2640; i += 320) {
        int c8 = i % 20; int xl = (i / 20) % 66; int r = i / 1320;
        int xg = xl - 1, yg = y + r - 1;
        short8 v = {};
        if (xg >= 0 && xg < 64 && yg >= 0) {
            const float* p = hin + (((size_t)(b * 64 + yg)) * 64 + xg) * 160 + c8 * 8;
            v = pack8_relu(*(const float4*)p, *(const float4*)(p + 4));
        }
        *(short8*)&in_s[(r * 66 + xl) * 168 + c8 * 8] = v;
    }
    __syncthreads();

    int lane = t & 63, w = t >> 6;
    int lx = lane & 15, q = lane >> 4;
    f32x4 acc[4][4] = {};
    const short* wl = wP + lx * 32 + q * 8;
    const int dxs[5] = {-1, 0, 1, -1, 0};
    const int rws[5] = {0, 0, 0, 1, 1};
    #pragma unroll
    for (int tap = 0; tap < 5; ++tap) {
        int rb0 = (rws[tap] * 66 + 1 + dxs[tap] + lx) * 168 + q * 8;
        #pragma unroll
        for (int k5 = 0; k5 < 5; ++k5) {
            const short* wk = wl + (tap * 5 + k5) * 10240;
            short8 aF[4], bF[4];
            aF[0] = *(const short8*)(wk + (32 * w) * 32);
            aF[1] = *(const short8*)(wk + (32 * w + 16) * 32);
            aF[2] = *(const short8*)(wk + (160 + 32 * w) * 32);
            aF[3] = *(const short8*)(wk + (176 + 32 * w) * 32);
            int rb = rb0 + k5 * 32;
            #pragma unroll
            for (int nt = 0; nt < 4; ++nt)
                bF[nt] = *(const short8*)&in_s[rb + nt * 16 * 168];
            #pragma unroll
            for (int mt = 0; mt < 4; ++mt)
                #pragma unroll
                for (int nt = 0; nt < 4; ++nt)
                    acc[mt][nt] = __builtin_amdgcn_mfma_f32_16x16x32_bf16(
                        aF[mt], bF[nt], acc[mt][nt], 0, 0, 0);
        }
    }
    // epilogue: in-register gating + float4 residual rmw (no barrier needed)
    size_t rowbase = ((size_t)(b * 64 + y)) * 64 * 160;
    #pragma unroll
    for (int mt = 0; mt < 2; ++mt) {
        int c0 = 32 * w + mt * 16 + q * 4;
        #pragma unroll
        for (int nt = 0; nt < 4; ++nt) {
            int px = nt * 16 + lx;
            size_t off = rowbase + (size_t)px * 160 + c0;
            float4 ho = *(const float4*)&hin[off];
            float4 o;
            o.x = ho.x + tanhf(acc[mt][nt][0]) * (1.f / (1.f + expf(-acc[mt + 2][nt][0])));
            o.y = ho.y + tanhf(acc[mt][nt][1]) * (1.f / (1.f + expf(-acc[mt + 2][nt][1])));
            o.z = ho.z + tanhf(acc[mt][nt][2]) * (1.f / (1.f + expf(-acc[mt + 2][nt][2])));
            o.w = ho.w + tanhf(acc[mt][nt][3]) * (1.f / (1.f + expf(-acc[mt + 2][nt][3])));
            *(float4*)&hout[off] = o;
        }
    }
}

__device__ __forceinline__ float softplusf_(float z) {
    return fmaxf(z, 0.f) + log1pf(expf(-fabsf(z)));
}
__device__ __forceinline__ float sigmoidf_(float z) {
    return 1.f / (1.f + expf(-z));
}

// fused head: relu -> conv1x1(W1) -> relu -> conv1x1(W2) -> DMOL -> atomicAdd.
// grid (64,16) = (y,b), block 320 (5 waves).
__global__ __launch_bounds__(320) void k_head(const float* __restrict__ hin,
                                              const short* __restrict__ W1P,
                                              const short* __restrict__ W2P,
                                              const float* __restrict__ X,
                                              float* __restrict__ out) {
    __shared__ char arenaA[29696];        // hls (21504) then Pls(26624)+lpls(3072)
    __shared__ short h2ls[64 * 168];      // 21504 B
    short* hls = (short*)arenaA;          // [px][ic pad168] bf16 relu(h)
    float* Pls = (float*)arenaA;          // [px][c pad104] fp32 params
    float* lpls = (float*)(arenaA + 26624); // [px][m pad12]
    int y = blockIdx.x, b = blockIdx.y;
    int t = threadIdx.x;
    size_t rowbase = ((size_t)(b * 64 + y)) * 64 * 160;
    // stage relu(h) bf16
    for (int i = t; i < 1280; i += 320) {
        int c8 = i % 20; int px = i / 20;
        const float* p = hin + rowbase + (size_t)px * 160 + c8 * 8;
        *(short8*)&hls[px * 168 + c8 * 8] = pack8_relu(*(const float4*)p, *(const float4*)(p + 4));
    }
    __syncthreads();
    int lane = t & 63, w = t >> 6;
    int lx = lane & 15, q = lane >> 4;
    // GEMM1: h2 = relu(W1 * relu(h))
    {
        f32x4 acc[2][4] = {};
        const short* wl = W1P + lx * 32 + q * 8;
        #pragma unroll
        for (int kc = 0; kc < 5; ++kc) {
            short8 aF[2], bF[4];
            aF[0] = *(const short8*)(wl + (kc * 160 + 32 * w) * 32);
            aF[1] = *(const short8*)(wl + (kc * 160 + 32 * w + 16) * 32);
            #pragma unroll
            for (int nt = 0; nt < 4; ++nt)
                bF[nt] = *(const short8*)&hls[(nt * 16 + lx) * 168 + kc * 32 + q * 8];
            #pragma unroll
            for (int mt = 0; mt < 2; ++mt)
                #pragma unroll
                for (int nt = 0; nt < 4; ++nt)
                    acc[mt][nt] = __builtin_amdgcn_mfma_f32_16x16x32_bf16(
                        aF[mt], bF[nt], acc[mt][nt], 0, 0, 0);
        }
        #pragma unroll
        for (int mt = 0; mt < 2; ++mt) {
            int c0 = 32 * w + mt * 16 + q * 4;
            #pragma unroll
            for (int nt = 0; nt < 4; ++nt) {
                int px = nt * 16 + lx;
                short4v s;
                s[0] = f2bf(fmaxf(acc[mt][nt][0], 0.f));
                s[1] = f2bf(fmaxf(acc[mt][nt][1], 0.f));
                s[2] = f2bf(fmaxf(acc[mt][nt][2], 0.f));
                s[3] = f2bf(fmaxf(acc[mt][nt][3], 0.f));
                *(short4v*)&h2ls[px * 168 + c0] = s;
            }
        }
    }
    __syncthreads();
    // GEMM2: params = W2 * h2   (oc padded to 160; only c<100 stored)
    {
        f32x4 acc[2][4] = {};
        const short* wl = W2P + lx * 32 + q * 8;
        #pragma unroll
        for (int kc = 0; kc < 5; ++kc) {
            short8 aF[2], bF[4];
            aF[0] = *(const short8*)(wl + (kc * 160 + 32 * w) * 32);
            aF[1] = *(const short8*)(wl + (kc * 160 + 32 * w + 16) * 32);
            #pragma unroll
            for (int nt = 0; nt < 4; ++nt)
                bF[nt] = *(const short8*)&h2ls[(nt * 16 + lx) * 168 + kc * 32 + q * 8];
            #pragma unroll
            for (int mt = 0; mt < 2; ++mt)
                #pragma unroll
                for (int nt = 0; nt < 4; ++nt)
                    acc[mt][nt] = __builtin_amdgcn_mfma_f32_16x16x32_bf16(
                        aF[mt], bF[nt], acc[mt][nt], 0, 0, 0);
        }
        #pragma unroll
        for (int mt = 0; mt < 2; ++mt) {
            int c0 = 32 * w + mt * 16 + q * 4;
            if (c0 < 100) {
                #pragma unroll
                for (int nt = 0; nt < 4; ++nt) {
                    int px = nt * 16 + lx;
                    float4 o;
                    o.x = acc[mt][nt][0]; o.y = acc[mt][nt][1];
                    o.z = acc[mt][nt][2]; o.w = acc[mt][nt][3];
                    *(float4*)&Pls[px * 104 + c0] = o;
                }
            }
        }
    }
    __syncthreads();
    // DMOL: 640 (px, mixture) tasks over 320 threads
    const float LOG127P5 = 4.8481163504f;
    #pragma unroll
    for (int it = 0; it < 2; ++it) {
        int tk = t + it * 320;
        int px = tk & 63, m = tk >> 6;
        const float* pp = &Pls[px * 104];
        float xs[3];
        #pragma unroll
        for (int c = 0; c < 3; ++c)
            xs[c] = X[((size_t)(b * 3 + c)) * 4096 + (size_t)y * 64 + px];
        float mx = pp[0];
        #pragma unroll
        for (int j = 1; j < 10; ++j) mx = fmaxf(mx, pp[j]);
        float se = 0.f;
        #pragma unroll
        for (int j = 0; j < 10; ++j) se += expf(pp[j] - mx);
        float lse = mx + logf(se);
        float sum = pp[m] - lse;
        float mean0 = pp[10 + m];
        float mean1 = pp[40 + m];
        float mean2 = pp[70 + m];
        float ls0 = fmaxf(pp[20 + m], -7.f);
        float ls1 = fmaxf(pp[50 + m], -7.f);
        float ls2 = fmaxf(pp[80 + m], -7.f);
        float c0 = tanhf(pp[30 + m]);
        float c1 = tanhf(pp[60 + m]);
        float c2 = tanhf(pp[90 + m]);
        float mu[3], lsv[3];
        mu[0] = mean0;
        mu[1] = mean1 + c0 * xs[0];
        mu[2] = mean2 + c1 * xs[0] + c2 * xs[1];
        lsv[0] = ls0; lsv[1] = ls1; lsv[2] = ls2;
        #pragma unroll
        for (int ci = 0; ci < 3; ++ci) {
            float cent = xs[ci] - mu[ci];
            float inv = expf(-lsv[ci]);
            float plus_in = inv * (cent + 1.f / 255.f);
            float min_in = inv * (cent - 1.f / 255.f);
            float cdf_delta = sigmoidf_(plus_in) - sigmoidf_(min_in);
            float log_cdf_plus = plus_in - softplusf_(plus_in);
            float log_om_cdf = -softplusf_(min_in);
            float mid = inv * cent;
            float log_pdf_mid = mid - lsv[ci] - 2.f * softplusf_(mid);
            float lpi = (cdf_delta > 1e-5f) ? logf(fmaxf(cdf_delta, 1e-12f))
                                            : (log_pdf_mid - LOG127P5);
            float lpc = (xs[ci] < -0.999f) ? log_cdf_plus
                       : ((xs[ci] > 0.999f) ? log_om_cdf : lpi);
            sum += lpc;
        }
        lpls[px * 12 + m] = sum;
    }
    __syncthreads();
    if (t < 64) {
        int px = t;
        float mx2 = lpls[px * 12];
        #pragma unroll
        for (int m = 1; m < 10; ++m) mx2 = fmaxf(mx2, lpls[px * 12 + m]);
        float se2 = 0.f;
        #pragma unroll
        for (int m = 0; m < 10; ++m) se2 += expf(lpls[px * 12 + m] - mx2);
        float lp = mx2 + logf(se2);
        #pragma unroll
        for (int off = 32; off > 0; off >>= 1) lp += __shfl_down(lp, off, 64);
        if (t == 0) atomicAdd(&out[b], lp);
    }
}

extern "C" void kernel_launch(void* const* d_in, const int* in_sizes, int n_in,
                              void* d_out, int out_size, void* d_ws, size_t ws_size,
                              hipStream_t stream) {
    const float* samples = (const float*)d_in[0];
    const float* w_in    = (const float*)d_in[1];
    const float* w_blk   = (const float*)d_in[2];
    const float* w_out1  = (const float*)d_in[3];
    const float* w_out2  = (const float*)d_in[4];
    char* ws = (char*)d_ws;
    float* X    = (float*)(ws + X_OFF);
    short* WINP = (short*)(ws + WINP_OFF);
    short* W1P  = (short*)(ws + W1P_OFF);
    short* W2P  = (short*)(ws + W2P_OFF);
    short* WPB  = (short*)(ws + WPB_OFF);
    float* HA   = (float*)(ws + HA_OFF);
    float* HB   = (float*)(ws + HB_OFF);
    float* fout = (float*)d_out;

    k_prep<<<768, 256, 0, stream>>>(samples, X, 16 * 3 * 4096);
    k_twb<<<5000, 256, 0, stream>>>(w_blk, WPB);
    k_twin<<<60, 256, 0, stream>>>(w_in, WINP);
    k_tw1<<<100, 256, 0, stream>>>(w_out1, W1P);
    k_tw2<<<100, 256, 0, stream>>>(w_out2, W2P);

    k_convin<<<dim3(64, 16), 320, 0, stream>>>(X, WINP, HA);

    float* a = HA; float* bq = HB;
    for (int i = 0; i < 5; i++) {
        k_blk<<<dim3(64, 16), 320, 0, stream>>>(a, bq, WPB + (size_t)i * 25 * 320 * 32);
        float* tmp = a; a = bq; bq = tmp;
    }
    // final h is in HB (a points to it after 5 swaps)
    hipMemsetAsync(d_out, 0, (size_t)out_size * sizeof(float), stream);
    k_head<<<dim3(64, 16), 320, 0, stream>>>(a, W1P, W2P, X, fout);
}

// Round 4
// 448.187 us; speedup vs baseline: 10.5450x; 1.1572x over previous
//
#include <hip/hip_runtime.h>
#include <math.h>

// ---------------------------------------------------------------------------
// PixelCNN (5 gated residual blocks) + DMOL logprob.  Round 4:
//   - h fp32 channel-last [b][y][x][160] single stream (round-3 structure)
//   - NEW: fast transcendentals (v_exp/v_log/v_rcp) for gating + DMOL
//   - NEW: v_perm-based bf16 pair packing in all staging paths
// ---------------------------------------------------------------------------

using short8  = __attribute__((ext_vector_type(8))) short;
using short4v = __attribute__((ext_vector_type(4))) short;
using f32x4   = __attribute__((ext_vector_type(4))) float;

static constexpr float L2E = 1.44269504088896f;   // log2(e)
static constexpr float LN2 = 0.69314718055995f;   // ln(2)

__device__ __forceinline__ float fexp2(float x) { return __builtin_amdgcn_exp2f(x); }
__device__ __forceinline__ float flog2(float x) { return __builtin_amdgcn_logf(x); }
__device__ __forceinline__ float frcp(float x)  { return __builtin_amdgcn_rcpf(x); }
__device__ __forceinline__ float fexp(float x)  { return fexp2(x * L2E); }
__device__ __forceinline__ float flog(float x)  { return flog2(x) * LN2; }
__device__ __forceinline__ float fsigmoid(float x) { return frcp(1.f + fexp2(-x * L2E)); }
__device__ __forceinline__ float ftanh(float x)    { return 1.f - 2.f * frcp(1.f + fexp2(x * (2.f * L2E))); }
__device__ __forceinline__ float fsoftplus(float z) {
    float e = fexp2(-fabsf(z) * L2E);
    return fmaxf(z, 0.f) + flog2(1.f + e) * LN2;
}

// pack two fp32 -> packed bf16 pair (a in low, b in high); round-to-nearest (ties down)
__device__ __forceinline__ unsigned pk_bf16(float a, float b) {
    union { float f; unsigned u; } ua, ub; ua.f = a; ub.f = b;
    return __builtin_amdgcn_perm(ub.u + 0x7fffu, ua.u + 0x7fffu, 0x07060302u);
}

__device__ __forceinline__ short f2bf(float f) {
    union { float f; unsigned u; } v; v.f = f;
    unsigned r = (v.u + 0x7fffu + ((v.u >> 16) & 1u)) >> 16;
    return (short)r;
}

__device__ __forceinline__ short8 pack8_relu(float4 a, float4 b) {
    union { short8 s; unsigned u[4]; } r;
    r.u[0] = pk_bf16(fmaxf(a.x, 0.f), fmaxf(a.y, 0.f));
    r.u[1] = pk_bf16(fmaxf(a.z, 0.f), fmaxf(a.w, 0.f));
    r.u[2] = pk_bf16(fmaxf(b.x, 0.f), fmaxf(b.y, 0.f));
    r.u[3] = pk_bf16(fmaxf(b.z, 0.f), fmaxf(b.w, 0.f));
    return r.s;
}

// workspace layout (bytes), 16B-aligned
static constexpr size_t X_OFF    = 0;             // 16*3*4096*4    = 786432
static constexpr size_t WINP_OFF = 786432;        // 3*160*32*2     = 30720
static constexpr size_t W1P_OFF  = 817152;        // 5*160*32*2     = 51200
static constexpr size_t W2P_OFF  = 868352;        // 5*160*32*2     = 51200
static constexpr size_t WPB_OFF  = 919552;        // 5*25*320*32*2  = 2560000
static constexpr size_t HA_OFF   = 3479552;       // 16*4096*160*4  = 41943040
static constexpr size_t HB_OFF   = 45422592;      // 41943040  (end ~87.4 MB)

__global__ void k_prep(const float* __restrict__ s, float* __restrict__ x, int n) {
    int i = blockIdx.x * 256 + threadIdx.x;
    if (i < n) x[i] = 2.f * s[i] - 1.f;
}

// w_blk (5,320,160,3,3) -> bf16 wP[i][kt=tap*5+icb][oc320][icl32]
__global__ void k_twb(const float* __restrict__ w, short* __restrict__ wP) {
    int idx = blockIdx.x * 256 + threadIdx.x;
    if (idx >= 5 * 25 * 320 * 32) return;
    int icl = idx & 31;
    int oc  = (idx >> 5) % 320;
    int kt  = ((idx >> 5) / 320) % 25;
    int i   = idx / (25 * 320 * 32);
    int tap = kt / 5, ic = (kt % 5) * 32 + icl;
    const int ky[5] = {0,0,0,1,1}, kx[5] = {0,1,2,0,1};
    float v = w[(((size_t)(i * 320 + oc) * 160 + ic) * 3 + ky[tap]) * 3 + kx[tap]];
    wP[idx] = f2bf(v);
}

// w_in (160,3,7,7) -> WINP[kc3][oc160][icl32], k=tap*3+ic over 24 mask-A taps, pad to 96
__global__ void k_twin(const float* __restrict__ w, short* __restrict__ wP) {
    int idx = blockIdx.x * 256 + threadIdx.x;
    if (idx >= 3 * 160 * 32) return;
    int icl = idx & 31;
    int oc  = (idx >> 5) % 160;
    int kc  = idx / 5120;
    int k = kc * 32 + icl;
    short v = 0;
    if (k < 72) {
        int tap = k / 3, ic = k % 3;
        int ky = (tap < 21) ? tap / 7 : 3;
        int kx = (tap < 21) ? tap % 7 : tap - 21;
        v = f2bf(w[((oc * 3 + ic) * 7 + ky) * 7 + kx]);
    }
    wP[idx] = v;
}

// w_out1 (160,160,1,1) -> W1P[kc5][oc160][icl32]
__global__ void k_tw1(const float* __restrict__ w, short* __restrict__ wP) {
    int idx = blockIdx.x * 256 + threadIdx.x;
    if (idx >= 5 * 160 * 32) return;
    int icl = idx & 31;
    int oc  = (idx >> 5) % 160;
    int kc  = idx / 5120;
    wP[idx] = f2bf(w[oc * 160 + kc * 32 + icl]);
}

// w_out2 (100,160,1,1) -> W2P[kc5][oc160 pad][icl32]
__global__ void k_tw2(const float* __restrict__ w, short* __restrict__ wP) {
    int idx = blockIdx.x * 256 + threadIdx.x;
    if (idx >= 5 * 160 * 32) return;
    int icl = idx & 31;
    int oc  = (idx >> 5) % 160;
    int kc  = idx / 5120;
    wP[idx] = (oc < 100) ? f2bf(w[oc * 160 + kc * 32 + icl]) : (short)0;
}

// masked 7x7 input conv, MFMA. grid (64,16) = (y,b), block 320 (5 waves).
// M=160 (2 m-tiles/wave), N=64 (4 n-tiles), K=72 pad 96 (3 kc). Writes h fp32 CL.
__global__ __launch_bounds__(320) void k_convin(const float* __restrict__ X,
                                                const short* __restrict__ WINP,
                                                float* __restrict__ hout) {
    __shared__ float xls[3 * 4 * 72];   // [ic][r=ky][col], col = xg+3 (0..69)
    __shared__ short Bls[64 * 104];     // [px][k pad104]
    int y = blockIdx.x, b = blockIdx.y;
    int t = threadIdx.x;
    for (int i = t; i < 840; i += 320) {
        int col = i % 70; int r = (i / 70) % 4; int ic = i / 280;
        int xg = col - 3, yg = y + r - 3;
        float v = 0.f;
        if (xg >= 0 && xg < 64 && yg >= 0)
            v = X[((size_t)(b * 3 + ic) * 64 + yg) * 64 + xg];
        xls[(ic * 4 + r) * 72 + col] = v;
    }
    __syncthreads();
    for (int i = t; i < 6144; i += 320) {
        int k = i % 96; int px = i / 96;
        short v = 0;
        if (k < 72) {
            int tap = k / 3, ic = k % 3;
            int ky = (tap < 21) ? tap / 7 : 3;
            int kx = (tap < 21) ? tap % 7 : tap - 21;
            v = f2bf(xls[(ic * 4 + ky) * 72 + px + kx]);
        }
        Bls[px * 104 + k] = v;
    }
    __syncthreads();
    int lane = t & 63, w = t >> 6;
    int lx = lane & 15, q = lane >> 4;
    f32x4 acc[2][4] = {};
    const short* wl = WINP + lx * 32 + q * 8;
    #pragma unroll
    for (int kc = 0; kc < 3; ++kc) {
        short8 aF[2], bF[4];
        aF[0] = *(const short8*)(wl + (kc * 160 + 32 * w) * 32);
        aF[1] = *(const short8*)(wl + (kc * 160 + 32 * w + 16) * 32);
        #pragma unroll
        for (int nt = 0; nt < 4; ++nt)
            bF[nt] = *(const short8*)&Bls[(nt * 16 + lx) * 104 + kc * 32 + q * 8];
        #pragma unroll
        for (int mt = 0; mt < 2; ++mt)
            #pragma unroll
            for (int nt = 0; nt < 4; ++nt)
                acc[mt][nt] = __builtin_amdgcn_mfma_f32_16x16x32_bf16(
                    aF[mt], bF[nt], acc[mt][nt], 0, 0, 0);
    }
    size_t rowbase = ((size_t)(b * 64 + y)) * 64 * 160;
    #pragma unroll
    for (int mt = 0; mt < 2; ++mt) {
        int c0 = 32 * w + mt * 16 + q * 4;
        #pragma unroll
        for (int nt = 0; nt < 4; ++nt) {
            int px = nt * 16 + lx;
            float4 o;
            o.x = acc[mt][nt][0]; o.y = acc[mt][nt][1];
            o.z = acc[mt][nt][2]; o.w = acc[mt][nt][3];
            *(float4*)&hout[rowbase + (size_t)px * 160 + c0] = o;
        }
    }
}

// MFMA gated block conv on h fp32 CL. grid (64,16) = (y,b), block 320 (5 waves).
// Wave w: a-channels 32w..32w+31 (m-tiles 0,1), b-partners 160+32w.. (m-tiles 2,3).
__global__ __launch_bounds__(320, 4) void k_blk(const float* __restrict__ hin,
                                                float* __restrict__ hout,
                                                const short* __restrict__ wP) {
    __shared__ short in_s[2 * 66 * 168];   // [r][x 0..65][ic pad168] = 44352 B
    int y = blockIdx.x, b = blockIdx.y;
    int t = threadIdx.x;
    // stage rows y-1, y: relu(h) -> bf16 (x halo, zero-pad OOB)
    for (int i = t; i < 2640; i += 320) {
        int c8 = i % 20; int xl = (i / 20) % 66; int r = i / 1320;
        int xg = xl - 1, yg = y + r - 1;
        short8 v = {};
        if (xg >= 0 && xg < 64 && yg >= 0) {
            const float* p = hin + (((size_t)(b * 64 + yg)) * 64 + xg) * 160 + c8 * 8;
            v = pack8_relu(*(const float4*)p, *(const float4*)(p + 4));
        }
        *(short8*)&in_s[(r * 66 + xl) * 168 + c8 * 8] = v;
    }
    __syncthreads();

    int lane = t & 63, w = t >> 6;
    int lx = lane & 15, q = lane >> 4;
    f32x4 acc[4][4] = {};
    const short* wl = wP + lx * 32 + q * 8;
    const int dxs[5] = {-1, 0, 1, -1, 0};
    const int rws[5] = {0, 0, 0, 1, 1};
    #pragma unroll
    for (int tap = 0; tap < 5; ++tap) {
        int rb0 = (rws[tap] * 66 + 1 + dxs[tap] + lx) * 168 + q * 8;
        #pragma unroll
        for (int k5 = 0; k5 < 5; ++k5) {
            const short* wk = wl + (tap * 5 + k5) * 10240;
            short8 aF[4], bF[4];
            aF[0] = *(const short8*)(wk + (32 * w) * 32);
            aF[1] = *(const short8*)(wk + (32 * w + 16) * 32);
            aF[2] = *(const short8*)(wk + (160 + 32 * w) * 32);
            aF[3] = *(const short8*)(wk + (176 + 32 * w) * 32);
            int rb = rb0 + k5 * 32;
            #pragma unroll
            for (int nt = 0; nt < 4; ++nt)
                bF[nt] = *(const short8*)&in_s[rb + nt * 16 * 168];
            #pragma unroll
            for (int mt = 0; mt < 4; ++mt)
                #pragma unroll
                for (int nt = 0; nt < 4; ++nt)
                    acc[mt][nt] = __builtin_amdgcn_mfma_f32_16x16x32_bf16(
                        aF[mt], bF[nt], acc[mt][nt], 0, 0, 0);
        }
    }
    // epilogue: in-register gating (fast transcendentals) + float4 residual rmw
    size_t rowbase = ((size_t)(b * 64 + y)) * 64 * 160;
    #pragma unroll
    for (int mt = 0; mt < 2; ++mt) {
        int c0 = 32 * w + mt * 16 + q * 4;
        #pragma unroll
        for (int nt = 0; nt < 4; ++nt) {
            int px = nt * 16 + lx;
            size_t off = rowbase + (size_t)px * 160 + c0;
            float4 ho = *(const float4*)&hin[off];
            float4 o;
            o.x = ho.x + ftanh(acc[mt][nt][0]) * fsigmoid(acc[mt + 2][nt][0]);
            o.y = ho.y + ftanh(acc[mt][nt][1]) * fsigmoid(acc[mt + 2][nt][1]);
            o.z = ho.z + ftanh(acc[mt][nt][2]) * fsigmoid(acc[mt + 2][nt][2]);
            o.w = ho.w + ftanh(acc[mt][nt][3]) * fsigmoid(acc[mt + 2][nt][3]);
            *(float4*)&hout[off] = o;
        }
    }
}

// fused head: relu -> conv1x1(W1) -> relu -> conv1x1(W2) -> DMOL -> atomicAdd.
// grid (64,16) = (y,b), block 320 (5 waves).
__global__ __launch_bounds__(320) void k_head(const float* __restrict__ hin,
                                              const short* __restrict__ W1P,
                                              const short* __restrict__ W2P,
                                              const float* __restrict__ X,
                                              float* __restrict__ out) {
    __shared__ char arenaA[29696];        // hls (21504) then Pls(26624)+lpls(3072)
    __shared__ short h2ls[64 * 168];      // 21504 B
    short* hls = (short*)arenaA;          // [px][ic pad168] bf16 relu(h)
    float* Pls = (float*)arenaA;          // [px][c pad104] fp32 params
    float* lpls = (float*)(arenaA + 26624); // [px][m pad12]
    int y = blockIdx.x, b = blockIdx.y;
    int t = threadIdx.x;
    size_t rowbase = ((size_t)(b * 64 + y)) * 64 * 160;
    // stage relu(h) bf16
    for (int i = t; i < 1280; i += 320) {
        int c8 = i % 20; int px = i / 20;
        const float* p = hin + rowbase + (size_t)px * 160 + c8 * 8;
        *(short8*)&hls[px * 168 + c8 * 8] = pack8_relu(*(const float4*)p, *(const float4*)(p + 4));
    }
    __syncthreads();
    int lane = t & 63, w = t >> 6;
    int lx = lane & 15, q = lane >> 4;
    // GEMM1: h2 = relu(W1 * relu(h))
    {
        f32x4 acc[2][4] = {};
        const short* wl = W1P + lx * 32 + q * 8;
        #pragma unroll
        for (int kc = 0; kc < 5; ++kc) {
            short8 aF[2], bF[4];
            aF[0] = *(const short8*)(wl + (kc * 160 + 32 * w) * 32);
            aF[1] = *(const short8*)(wl + (kc * 160 + 32 * w + 16) * 32);
            #pragma unroll
            for (int nt = 0; nt < 4; ++nt)
                bF[nt] = *(const short8*)&hls[(nt * 16 + lx) * 168 + kc * 32 + q * 8];
            #pragma unroll
            for (int mt = 0; mt < 2; ++mt)
                #pragma unroll
                for (int nt = 0; nt < 4; ++nt)
                    acc[mt][nt] = __builtin_amdgcn_mfma_f32_16x16x32_bf16(
                        aF[mt], bF[nt], acc[mt][nt], 0, 0, 0);
        }
        #pragma unroll
        for (int mt = 0; mt < 2; ++mt) {
            int c0 = 32 * w + mt * 16 + q * 4;
            #pragma unroll
            for (int nt = 0; nt < 4; ++nt) {
                int px = nt * 16 + lx;
                union { short4v s; unsigned u[2]; } sv;
                sv.u[0] = pk_bf16(fmaxf(acc[mt][nt][0], 0.f), fmaxf(acc[mt][nt][1], 0.f));
                sv.u[1] = pk_bf16(fmaxf(acc[mt][nt][2], 0.f), fmaxf(acc[mt][nt][3], 0.f));
                *(short4v*)&h2ls[px * 168 + c0] = sv.s;
            }
        }
    }
    __syncthreads();
    // GEMM2: params = W2 * h2   (oc padded to 160; only c<100 stored)
    {
        f32x4 acc[2][4] = {};
        const short* wl = W2P + lx * 32 + q * 8;
        #pragma unroll
        for (int kc = 0; kc < 5; ++kc) {
            short8 aF[2], bF[4];
            aF[0] = *(const short8*)(wl + (kc * 160 + 32 * w) * 32);
            aF[1] = *(const short8*)(wl + (kc * 160 + 32 * w + 16) * 32);
            #pragma unroll
            for (int nt = 0; nt < 4; ++nt)
                bF[nt] = *(const short8*)&h2ls[(nt * 16 + lx) * 168 + kc * 32 + q * 8];
            #pragma unroll
            for (int mt = 0; mt < 2; ++mt)
                #pragma unroll
                for (int nt = 0; nt < 4; ++nt)
                    acc[mt][nt] = __builtin_amdgcn_mfma_f32_16x16x32_bf16(
                        aF[mt], bF[nt], acc[mt][nt], 0, 0, 0);
        }
        #pragma unroll
        for (int mt = 0; mt < 2; ++mt) {
            int c0 = 32 * w + mt * 16 + q * 4;
            if (c0 < 100) {
                #pragma unroll
                for (int nt = 0; nt < 4; ++nt) {
                    int px = nt * 16 + lx;
                    float4 o;
                    o.x = acc[mt][nt][0]; o.y = acc[mt][nt][1];
                    o.z = acc[mt][nt][2]; o.w = acc[mt][nt][3];
                    *(float4*)&Pls[px * 104 + c0] = o;
                }
            }
        }
    }
    __syncthreads();
    // DMOL: 640 (px, mixture) tasks over 320 threads (fast transcendentals)
    const float LOG127P5 = 4.8481163504f;   // ln(127.5)
    #pragma unroll
    for (int it = 0; it < 2; ++it) {
        int tk = t + it * 320;
        int px = tk & 63, m = tk >> 6;
        const float* pp = &Pls[px * 104];
        float xs[3];
        #pragma unroll
        for (int c = 0; c < 3; ++c)
            xs[c] = X[((size_t)(b * 3 + c)) * 4096 + (size_t)y * 64 + px];
        float mx = pp[0];
        #pragma unroll
        for (int j = 1; j < 10; ++j) mx = fmaxf(mx, pp[j]);
        float se = 0.f;
        #pragma unroll
        for (int j = 0; j < 10; ++j) se += fexp(pp[j] - mx);
        float lse = mx + flog(se);
        float sum = pp[m] - lse;
        float mean0 = pp[10 + m];
        float mean1 = pp[40 + m];
        float mean2 = pp[70 + m];
        float ls0 = fmaxf(pp[20 + m], -7.f);
        float ls1 = fmaxf(pp[50 + m], -7.f);
        float ls2 = fmaxf(pp[80 + m], -7.f);
        float c0 = ftanh(pp[30 + m]);
        float c1 = ftanh(pp[60 + m]);
        float c2 = ftanh(pp[90 + m]);
        float mu[3], lsv[3];
        mu[0] = mean0;
        mu[1] = mean1 + c0 * xs[0];
        mu[2] = mean2 + c1 * xs[0] + c2 * xs[1];
        lsv[0] = ls0; lsv[1] = ls1; lsv[2] = ls2;
        #pragma unroll
        for (int ci = 0; ci < 3; ++ci) {
            float cent = xs[ci] - mu[ci];
            float inv = fexp(-lsv[ci]);
            float plus_in = inv * (cent + 1.f / 255.f);
            float min_in = inv * (cent - 1.f / 255.f);
            float cdf_delta = fsigmoid(plus_in) - fsigmoid(min_in);
            float log_cdf_plus = plus_in - fsoftplus(plus_in);
            float log_om_cdf = -fsoftplus(min_in);
            float mid = inv * cent;
            float log_pdf_mid = mid - lsv[ci] - 2.f * fsoftplus(mid);
            float lpi = (cdf_delta > 1e-5f) ? flog(fmaxf(cdf_delta, 1e-12f))
                                            : (log_pdf_mid - LOG127P5);
            float lpc = (xs[ci] < -0.999f) ? log_cdf_plus
                       : ((xs[ci] > 0.999f) ? log_om_cdf : lpi);
            sum += lpc;
        }
        lpls[px * 12 + m] = sum;
    }
    __syncthreads();
    if (t < 64) {
        int px = t;
        float mx2 = lpls[px * 12];
        #pragma unroll
        for (int m = 1; m < 10; ++m) mx2 = fmaxf(mx2, lpls[px * 12 + m]);
        float se2 = 0.f;
        #pragma unroll
        for (int m = 0; m < 10; ++m) se2 += fexp(lpls[px * 12 + m] - mx2);
        float lp = mx2 + flog(se2);
        #pragma unroll
        for (int off = 32; off > 0; off >>= 1) lp += __shfl_down(lp, off, 64);
        if (t == 0) atomicAdd(&out[b], lp);
    }
}

extern "C" void kernel_launch(void* const* d_in, const int* in_sizes, int n_in,
                              void* d_out, int out_size, void* d_ws, size_t ws_size,
                              hipStream_t stream) {
    const float* samples = (const float*)d_in[0];
    const float* w_in    = (const float*)d_in[1];
    const float* w_blk   = (const float*)d_in[2];
    const float* w_out1  = (const float*)d_in[3];
    const float* w_out2  = (const float*)d_in[4];
    char* ws = (char*)d_ws;
    float* X    = (float*)(ws + X_OFF);
    short* WINP = (short*)(ws + WINP_OFF);
    short* W1P  = (short*)(ws + W1P_OFF);
    short* W2P  = (short*)(ws + W2P_OFF);
    short* WPB  = (short*)(ws + WPB_OFF);
    float* HA   = (float*)(ws + HA_OFF);
    float* HB   = (float*)(ws + HB_OFF);
    float* fout = (float*)d_out;

    k_prep<<<768, 256, 0, stream>>>(samples, X, 16 * 3 * 4096);
    k_twb<<<5000, 256, 0, stream>>>(w_blk, WPB);
    k_twin<<<60, 256, 0, stream>>>(w_in, WINP);
    k_tw1<<<100, 256, 0, stream>>>(w_out1, W1P);
    k_tw2<<<100, 256, 0, stream>>>(w_out2, W2P);

    k_convin<<<dim3(64, 16), 320, 0, stream>>>(X, WINP, HA);

    float* a = HA; float* bq = HB;
    for (int i = 0; i < 5; i++) {
        k_blk<<<dim3(64, 16), 320, 0, stream>>>(a, bq, WPB + (size_t)i * 25 * 320 * 32);
        float* tmp = a; a = bq; bq = tmp;
    }
    // final h is in HB (a points to it after 5 swaps)
    hipMemsetAsync(d_out, 0, (size_t)out_size * sizeof(float), stream);
    k_head<<<dim3(64, 16), 320, 0, stream>>>(a, W1P, W2P, X, fout);
}